// Round 4
// baseline (828.746 us; speedup 1.0000x reference)
//
#include <hip/hip_runtime.h>

#define VOCAB 10000
#define HIDDEN 256
#define BATCH 32
#define SEQ 256
#define NPAD 10112            // 79 * 128
#define NTILES 79
#define MTILES 64             // 8192 / 128
#define LOGITS_ELEMS 81920000LL
#define TR_BLOCKS 628         // 157 v-tiles * 4 h-tiles
#define PREP_BLOCKS 707       // + 79 Wb blocks (128 rows each)

typedef __attribute__((ext_vector_type(8))) short short8;
typedef __attribute__((ext_vector_type(4))) float f32x4;

static __device__ __forceinline__ unsigned short f32_to_bf16(float f) {
    unsigned u = __float_as_uint(f);
    u += 0x7fffu + ((u >> 16) & 1u);   // round-to-nearest-even
    return (unsigned short)(u >> 16);
}

// ---------------------------------------------------------------------------
// Kernel 1 (merged): blocks [0,628): W_ihT = W_ih^T via 64x64 LDS tile;
// blocks [628,707): Wb = bf16(W_out) padded to NPAD rows (128 rows/block).
// ---------------------------------------------------------------------------
__global__ __launch_bounds__(256) void prep_kernel(const float* __restrict__ W_ih,
                                                   float* __restrict__ W_ihT,
                                                   const float* __restrict__ W_out,
                                                   unsigned short* __restrict__ Wb) {
    __shared__ float tile[64][65];          // +1 pad: conflict-free transpose read
    const int t = threadIdx.x;
    if (blockIdx.x < TR_BLOCKS) {
        const int v0   = (blockIdx.x >> 2) * 64;
        const int h0   = (blockIdx.x & 3) * 64;
        const int lane = t & 63;
        const int wv   = t >> 6;            // 0..3
#pragma unroll
        for (int i = 0; i < 16; ++i) {
            const int row = i * 4 + wv;     // h offset within tile
            const int v   = v0 + lane;
            if (v < VOCAB)
                tile[row][lane] = W_ih[(long)(h0 + row) * VOCAB + v];
        }
        __syncthreads();
#pragma unroll
        for (int i = 0; i < 16; ++i) {
            const int vrow = i * 4 + wv;    // v offset within tile
            const int v    = v0 + vrow;
            if (v < VOCAB)
                W_ihT[(long)v * HIDDEN + h0 + lane] = tile[lane][vrow];
        }
    } else {
        const int n0 = (blockIdx.x - TR_BLOCKS) * 128;
#pragma unroll 4
        for (int r = 0; r < 128; ++r) {
            const int n = n0 + r;
            const float v = (n < VOCAB) ? W_out[(long)n * HIDDEN + t] : 0.f;
            Wb[(long)n * HIDDEN + t] = f32_to_bf16(v);
        }
    }
}

// ---------------------------------------------------------------------------
// Kernel 2: RNN scan, wave-local decomposition.
// One block (512 thr, 8 waves) per batch row.
//   lane l of wave w owns row h = 32w + (l&31), k-half kh = l>>5:
//   128 W_hh floats in VGPRs.  Cross-k reduce = ONE __shfl_xor(s,32).
//   tanh/bias/x-gather replicated per lane-half -> all 8 waves run their own
//   tails in parallel.  hbuf double-buffered -> ONE __syncthreads() per step.
// ---------------------------------------------------------------------------
__global__ __launch_bounds__(512, 2) void scan_kernel(
        const int*   __restrict__ inputs,   // (32, 256)
        const float* __restrict__ state,    // (1, 32, 256)
        const float* __restrict__ W_hh,     // (256, 256)
        const float* __restrict__ b_ih,
        const float* __restrict__ b_hh,
        const float* __restrict__ W_ihT,    // (10000, 256)
        unsigned short* __restrict__ Ybf,   // (8192, 256) bf16
        float* __restrict__ hout)           // (32, 256)
{
    __shared__ float hbuf[2][HIDDEN];

    const int b  = blockIdx.x;
    const int t  = threadIdx.x;
    const int wv = t >> 6;          // wave 0..7
    const int l  = t & 63;
    const int l5 = l & 31;
    const int kh = l >> 5;          // k-half 0/1
    const int h  = 32 * wv + l5;    // owned row (replicated across kh)

    // 128 weights/lane: W_hh[h][128*kh .. 128*kh+127]
    float w[128];
    {
        const float* src = W_hh + (long)h * HIDDEN + 128 * kh;
#pragma unroll
        for (int k4 = 0; k4 < 32; ++k4) {
            const float4 v = *(const float4*)(src + 4 * k4);
            w[4 * k4 + 0] = v.x;
            w[4 * k4 + 1] = v.y;
            w[4 * k4 + 2] = v.z;
            w[4 * k4 + 3] = v.w;
        }
    }

    const float biasv = b_ih[h] + b_hh[h];
    if (l < 32) hbuf[0][h] = state[b * HIDDEN + h];
    const int tok0 = inputs[b * SEQ];
    float xcur = W_ihT[(long)tok0 * HIDDEN + h];
    __syncthreads();

    int cur = 0;
    for (int step = 0; step < SEQ; ++step) {
        float xnext = 0.f;
        if (step + 1 < SEQ) {
            const int tokn = inputs[b * SEQ + step + 1];
            xnext = W_ihT[(long)tokn * HIDDEN + h];
        }

        // 4 independent FMA chains over this lane's 128 k-values
        float a0 = 0.f, a1 = 0.f, a2 = 0.f, a3 = 0.f;
        const float* hb = &hbuf[cur][128 * kh];
#pragma unroll
        for (int k16 = 0; k16 < 8; ++k16) {
            const float4 h0 = *(const float4*)(hb + 16 * k16 + 0);
            const float4 h1 = *(const float4*)(hb + 16 * k16 + 4);
            const float4 h2 = *(const float4*)(hb + 16 * k16 + 8);
            const float4 h3 = *(const float4*)(hb + 16 * k16 + 12);
            const int kb = 16 * k16;
            a0 = fmaf(w[kb +  0], h0.x, a0);
            a0 = fmaf(w[kb +  1], h0.y, a0);
            a0 = fmaf(w[kb +  2], h0.z, a0);
            a0 = fmaf(w[kb +  3], h0.w, a0);
            a1 = fmaf(w[kb +  4], h1.x, a1);
            a1 = fmaf(w[kb +  5], h1.y, a1);
            a1 = fmaf(w[kb +  6], h1.z, a1);
            a1 = fmaf(w[kb +  7], h1.w, a1);
            a2 = fmaf(w[kb +  8], h2.x, a2);
            a2 = fmaf(w[kb +  9], h2.y, a2);
            a2 = fmaf(w[kb + 10], h2.z, a2);
            a2 = fmaf(w[kb + 11], h2.w, a2);
            a3 = fmaf(w[kb + 12], h3.x, a3);
            a3 = fmaf(w[kb + 13], h3.y, a3);
            a3 = fmaf(w[kb + 14], h3.z, a3);
            a3 = fmaf(w[kb + 15], h3.w, a3);
        }
        float s = (a0 + a1) + (a2 + a3);
        s += __shfl_xor(s, 32);               // combine the two k-halves

        const float hnew = tanhf(s + xcur + biasv);   // replicated both halves
        if (l < 32) {
            hbuf[cur ^ 1][h] = hnew;
            Ybf[((long)step * BATCH + b) * HIDDEN + h] = f32_to_bf16(hnew);
        }
        xcur = xnext;
        cur ^= 1;
        __syncthreads();   // writes of hbuf[cur] visible; all reads of old buf done
    }

    if (l < 32) hout[b * HIDDEN + h] = hbuf[cur][h];
}

// ---------------------------------------------------------------------------
// Kernel 3: logits = Y(bf16) @ Wb^T + b_out — unchanged from round 2 (passed):
// 128x128 tile, BK=64, T2 XOR swizzle (pre-swizzled global source + linear
// global_load_lds dest + same XOR on ds_read), double-buffered LDS with
// stage(kb+1)-before-compute(kb), nontemporal C stores.
// ---------------------------------------------------------------------------
__global__ __launch_bounds__(256) void gemm_kernel(
        const unsigned short* __restrict__ A,   // (8192, 256) bf16
        const unsigned short* __restrict__ B,   // (10112, 256) bf16
        const float* __restrict__ bias,         // (10000,)
        float* __restrict__ C)                  // (8192, 10000) f32
{
    __shared__ __align__(16) unsigned short lA[2][128 * 64];
    __shared__ __align__(16) unsigned short lB[2][128 * 64];

    const int t     = threadIdx.x;
    const int bid   = blockIdx.x;
    const int ntile = bid % NTILES;
    const int mtile = bid / NTILES;
    const long m0   = (long)mtile * 128;
    const long n0   = (long)ntile * 128;
    const int lane  = t & 63;
    const int wave  = t >> 6;
    const int wm    = (wave & 1) * 64;
    const int wn    = (wave >> 1) * 64;
    const int l15   = lane & 15;
    const int quad  = lane >> 4;

    const f32x4 zero = {0.f, 0.f, 0.f, 0.f};
    f32x4 acc[4][4];
#pragma unroll
    for (int i = 0; i < 4; ++i)
#pragma unroll
        for (int j = 0; j < 4; ++j)
            acc[i][j] = zero;

    auto stage = [&](int kb, int buf) {
#pragma unroll
        for (int it = 0; it < 4; ++it) {
            const int c   = it * 256 + t;    // 0..1023 = 128 rows x 8 chunks
            const int row = c >> 3;
            const int sk8 = (c & 7) ^ (row & 7);
            const unsigned short* ga = A + (m0 + row) * HIDDEN + kb * 64 + sk8 * 8;
            const unsigned short* gb = B + (n0 + row) * HIDDEN + kb * 64 + sk8 * 8;
            __builtin_amdgcn_global_load_lds(
                (const __attribute__((address_space(1))) void*)ga,
                (__attribute__((address_space(3))) void*)(&lA[buf][c * 8]), 16, 0, 0);
            __builtin_amdgcn_global_load_lds(
                (const __attribute__((address_space(1))) void*)gb,
                (__attribute__((address_space(3))) void*)(&lB[buf][c * 8]), 16, 0, 0);
        }
    };

    stage(0, 0);
    __syncthreads();                         // drains stage(0)

#pragma unroll
    for (int kb = 0; kb < 4; ++kb) {
        if (kb < 3) stage(kb + 1, (kb + 1) & 1);   // overlap loads with compute
        const unsigned short* bufA = lA[kb & 1];
        const unsigned short* bufB = lB[kb & 1];
#pragma unroll
        for (int ki = 0; ki < 2; ++ki) {
            short8 af[4], bf[4];
#pragma unroll
            for (int i = 0; i < 4; ++i) {
                const int ra = wm + 16 * i + l15;
                af[i] = *(const short8*)
                    &bufA[ra * 64 + (((ki * 4 + quad) ^ (ra & 7)) * 8)];
                const int rb = wn + 16 * i + l15;
                bf[i] = *(const short8*)
                    &bufB[rb * 64 + (((ki * 4 + quad) ^ (rb & 7)) * 8)];
            }
#pragma unroll
            for (int i = 0; i < 4; ++i)
#pragma unroll
                for (int j = 0; j < 4; ++j)
                    acc[i][j] = __builtin_amdgcn_mfma_f32_16x16x32_bf16(
                        af[i], bf[j], acc[i][j], 0, 0, 0);
        }
        if (kb < 3) __syncthreads();
    }

    // epilogue: C/D layout col = lane&15, row = quad*4 + reg.  Nontemporal:
    // C is never re-read; bypass L2.
#pragma unroll
    for (int j = 0; j < 4; ++j) {
        const long col = n0 + wn + 16 * j + l15;
        if (col < VOCAB) {
            const float bv = bias[col];
#pragma unroll
            for (int i = 0; i < 4; ++i) {
                const long row = m0 + wm + 16 * i + quad * 4;
                float* Cp = C + row * VOCAB + col;
#pragma unroll
                for (int r = 0; r < 4; ++r)
                    __builtin_nontemporal_store(acc[i][j][r] + bv,
                                                Cp + (long)r * VOCAB);
            }
        }
    }
}

// ---------------------------------------------------------------------------
extern "C" void kernel_launch(void* const* d_in, const int* in_sizes, int n_in,
                              void* d_out, int out_size, void* d_ws, size_t ws_size,
                              hipStream_t stream) {
    const int*   inputs = (const int*)  d_in[0];
    const float* state  = (const float*)d_in[1];
    const float* W_ih   = (const float*)d_in[2];
    const float* b_ih   = (const float*)d_in[3];
    const float* W_hh   = (const float*)d_in[4];
    const float* b_hh   = (const float*)d_in[5];
    const float* W_out  = (const float*)d_in[6];
    const float* b_out  = (const float*)d_in[7];
    float* out = (float*)d_out;

    char* ws = (char*)d_ws;
    float*          W_ihT = (float*)ws;                        // 10,240,000 B
    unsigned short* Wb    = (unsigned short*)(ws + 10240000);  //  5,177,344 B
    unsigned short* Ybf   = (unsigned short*)(ws + 15417344);  //  4,194,304 B

    prep_kernel<<<PREP_BLOCKS, 256, 0, stream>>>(W_ih, W_ihT, W_out, Wb);
    scan_kernel<<<BATCH, 512, 0, stream>>>(inputs, state, W_hh, b_ih, b_hh,
                                           W_ihT, Ybf, out + LOGITS_ELEMS);
    gemm_kernel<<<MTILES * NTILES, 256, 0, stream>>>(Ybf, Wb, b_out, out);
}

// Round 5
// 719.381 us; speedup vs baseline: 1.1520x; 1.1520x over previous
//
#include <hip/hip_runtime.h>

#define VOCAB 10000
#define HIDDEN 256
#define BATCH 32
#define SEQ 256
#define NPAD 10112            // 79 * 128
#define NTILES 79
#define MTILES 64             // 8192 / 128
#define LOGITS_ELEMS 81920000LL
#define TR_BLOCKS 628         // 157 v-tiles * 4 h-tiles
#define PREP_BLOCKS 707       // + 79 Wb blocks (128 rows each)

typedef __attribute__((ext_vector_type(8))) short short8;
typedef __attribute__((ext_vector_type(4))) float f32x4;

static __device__ __forceinline__ unsigned short f32_to_bf16(float f) {
    unsigned u = __float_as_uint(f);
    u += 0x7fffu + ((u >> 16) & 1u);   // round-to-nearest-even
    return (unsigned short)(u >> 16);
}

// ---------------------------------------------------------------------------
// Kernel 1 (merged): blocks [0,628): W_ihT = W_ih^T via 64x64 LDS tile;
// blocks [628,707): Wb = bf16(W_out) padded to NPAD rows (128 rows/block).
// ---------------------------------------------------------------------------
__global__ __launch_bounds__(256) void prep_kernel(const float* __restrict__ W_ih,
                                                   float* __restrict__ W_ihT,
                                                   const float* __restrict__ W_out,
                                                   unsigned short* __restrict__ Wb) {
    __shared__ float tile[64][65];          // +1 pad: conflict-free transpose read
    const int t = threadIdx.x;
    if (blockIdx.x < TR_BLOCKS) {
        const int v0   = (blockIdx.x >> 2) * 64;
        const int h0   = (blockIdx.x & 3) * 64;
        const int lane = t & 63;
        const int wv   = t >> 6;            // 0..3
#pragma unroll
        for (int i = 0; i < 16; ++i) {
            const int row = i * 4 + wv;     // h offset within tile
            const int v   = v0 + lane;
            if (v < VOCAB)
                tile[row][lane] = W_ih[(long)(h0 + row) * VOCAB + v];
        }
        __syncthreads();
#pragma unroll
        for (int i = 0; i < 16; ++i) {
            const int vrow = i * 4 + wv;    // v offset within tile
            const int v    = v0 + vrow;
            if (v < VOCAB)
                W_ihT[(long)v * HIDDEN + h0 + lane] = tile[lane][vrow];
        }
    } else {
        const int n0 = (blockIdx.x - TR_BLOCKS) * 128;
#pragma unroll 4
        for (int r = 0; r < 128; ++r) {
            const int n = n0 + r;
            const float v = (n < VOCAB) ? W_out[(long)n * HIDDEN + t] : 0.f;
            Wb[(long)n * HIDDEN + t] = f32_to_bf16(v);
        }
    }
}

// ---------------------------------------------------------------------------
// Kernel 2: RNN scan, wave-local, NAMED-REGISTER weights (spill-proof).
// One block (512 thr, 8 waves) per batch row.
//   lane l of wave w: rows h0,h1 = 32w + 2*(l&15) + {0,1}; k-chunk c = l>>4
//   (64 k-values).  Weights = 32 named float4 VGPRs — no array, SROA cannot
//   demote (round 4: float w[128] went to scratch, VGPR_Count=80, 382us).
//   Cross-chunk reduce: two __shfl_xor (16, 32).  One barrier/step.
//   hbuf chunks stored with a 32B/chunk skew (float offset 72c) so the 4
//   concurrent broadcast read streams hit disjoint bank sets (4i, 4i+8,
//   4i+16, 4i+24) — conflict-free; naive layout was a 4-way conflict.
//   Gather/tanh/stores only on the c==0 quarter (1/4 the x-gather traffic).
// ---------------------------------------------------------------------------
#define LDW(i) \
    const float4 wa##i = *(const float4*)(s0p + 4 * i); \
    const float4 wb##i = *(const float4*)(s1p + 4 * i);

#define FSTEP(i, aA, aB) { \
    const float4 hv = *(const float4*)(rb + 4 * i); \
    aA = fmaf(wa##i.x, hv.x, aA); aA = fmaf(wa##i.y, hv.y, aA); \
    aA = fmaf(wa##i.z, hv.z, aA); aA = fmaf(wa##i.w, hv.w, aA); \
    aB = fmaf(wb##i.x, hv.x, aB); aB = fmaf(wb##i.y, hv.y, aB); \
    aB = fmaf(wb##i.z, hv.z, aB); aB = fmaf(wb##i.w, hv.w, aB); }

__global__ __launch_bounds__(512, 2) void scan_kernel(
        const int*   __restrict__ inputs,   // (32, 256)
        const float* __restrict__ state,    // (1, 32, 256)
        const float* __restrict__ W_hh,     // (256, 256)
        const float* __restrict__ b_ih,
        const float* __restrict__ b_hh,
        const float* __restrict__ W_ihT,    // (10000, 256)
        unsigned short* __restrict__ Ybf,   // (8192, 256) bf16
        float* __restrict__ hout)           // (32, 256)
{
    __shared__ float hbuf[2][280];   // 4 chunks of 64 floats at offsets 72c

    const int b  = blockIdx.x;
    const int t  = threadIdx.x;
    const int wv = t >> 6;           // wave 0..7
    const int l  = t & 63;
    const int c  = l >> 4;           // k-chunk 0..3 (lane bits 4-5)
    const int rs = l & 15;           // row-slot
    const int h0 = 32 * wv + 2 * rs;
    const int h1 = h0 + 1;
    const int wpos = 72 * (h0 >> 6) + (h0 & 63);   // skewed hbuf position of h0

    const float* s0p = W_hh + (long)h0 * HIDDEN + 64 * c;
    const float* s1p = W_hh + (long)h1 * HIDDEN + 64 * c;
    LDW(0)  LDW(1)  LDW(2)  LDW(3)  LDW(4)  LDW(5)  LDW(6)  LDW(7)
    LDW(8)  LDW(9)  LDW(10) LDW(11) LDW(12) LDW(13) LDW(14) LDW(15)

    const float bias0 = b_ih[h0] + b_hh[h0];
    const float bias1 = b_ih[h1] + b_hh[h1];

    float x0 = 0.f, x1 = 0.f;
    if (c == 0) {
        *(float2*)&hbuf[0][wpos] = *(const float2*)&state[b * HIDDEN + h0];
        const int tok0 = inputs[b * SEQ];
        const float2 xv = *(const float2*)&W_ihT[(long)tok0 * HIDDEN + h0];
        x0 = xv.x; x1 = xv.y;
    }
    __syncthreads();

    int cur = 0;
    for (int step = 0; step < SEQ; ++step) {
        float xn0 = 0.f, xn1 = 0.f;
        if (c == 0 && step + 1 < SEQ) {
            const int tokn = inputs[b * SEQ + step + 1];
            const float2 xv = *(const float2*)&W_ihT[(long)tokn * HIDDEN + h0];
            xn0 = xv.x; xn1 = xv.y;
        }

        const float* rb = &hbuf[cur][72 * c];
        float a0 = 0.f, a1 = 0.f, b0 = 0.f, b1 = 0.f;   // 2 chains per row
        FSTEP(0,  a0, b0) FSTEP(1,  a1, b1) FSTEP(2,  a0, b0) FSTEP(3,  a1, b1)
        FSTEP(4,  a0, b0) FSTEP(5,  a1, b1) FSTEP(6,  a0, b0) FSTEP(7,  a1, b1)
        FSTEP(8,  a0, b0) FSTEP(9,  a1, b1) FSTEP(10, a0, b0) FSTEP(11, a1, b1)
        FSTEP(12, a0, b0) FSTEP(13, a1, b1) FSTEP(14, a0, b0) FSTEP(15, a1, b1)

        float s0 = a0 + a1;
        float s1 = b0 + b1;
        s0 += __shfl_xor(s0, 16); s0 += __shfl_xor(s0, 32);  // sum 4 k-chunks
        s1 += __shfl_xor(s1, 16); s1 += __shfl_xor(s1, 32);

        if (c == 0) {       // quarter-lane tail; all waves run theirs in parallel
            const float hn0 = tanhf(s0 + x0 + bias0);
            const float hn1 = tanhf(s1 + x1 + bias1);
            float2 hw; hw.x = hn0; hw.y = hn1;
            *(float2*)&hbuf[cur ^ 1][wpos] = hw;
            ushort2 y; y.x = f32_to_bf16(hn0); y.y = f32_to_bf16(hn1);
            *(ushort2*)&Ybf[((long)step * BATCH + b) * HIDDEN + h0] = y;
            x0 = xn0; x1 = xn1;
        }
        cur ^= 1;
        __syncthreads();    // hbuf[cur] visible; old buffer's readers done
    }

    if (c == 0)
        *(float2*)&hout[b * HIDDEN + h0] = *(const float2*)&hbuf[cur][wpos];
}

// ---------------------------------------------------------------------------
// Kernel 3: logits = Y(bf16) @ Wb^T + b_out — unchanged (passed rounds 2&4):
// 128x128 tile, BK=64, T2 XOR swizzle (pre-swizzled global source + linear
// global_load_lds dest + same XOR on ds_read), double-buffered LDS with
// stage(kb+1)-before-compute(kb), nontemporal C stores.
// ---------------------------------------------------------------------------
__global__ __launch_bounds__(256) void gemm_kernel(
        const unsigned short* __restrict__ A,   // (8192, 256) bf16
        const unsigned short* __restrict__ B,   // (10112, 256) bf16
        const float* __restrict__ bias,         // (10000,)
        float* __restrict__ C)                  // (8192, 10000) f32
{
    __shared__ __align__(16) unsigned short lA[2][128 * 64];
    __shared__ __align__(16) unsigned short lB[2][128 * 64];

    const int t     = threadIdx.x;
    const int bid   = blockIdx.x;
    const int ntile = bid % NTILES;
    const int mtile = bid / NTILES;
    const long m0   = (long)mtile * 128;
    const long n0   = (long)ntile * 128;
    const int lane  = t & 63;
    const int wave  = t >> 6;
    const int wm    = (wave & 1) * 64;
    const int wn    = (wave >> 1) * 64;
    const int l15   = lane & 15;
    const int quad  = lane >> 4;

    const f32x4 zero = {0.f, 0.f, 0.f, 0.f};
    f32x4 acc[4][4];
#pragma unroll
    for (int i = 0; i < 4; ++i)
#pragma unroll
        for (int j = 0; j < 4; ++j)
            acc[i][j] = zero;

    auto stage = [&](int kb, int buf) {
#pragma unroll
        for (int it = 0; it < 4; ++it) {
            const int c   = it * 256 + t;    // 0..1023 = 128 rows x 8 chunks
            const int row = c >> 3;
            const int sk8 = (c & 7) ^ (row & 7);
            const unsigned short* ga = A + (m0 + row) * HIDDEN + kb * 64 + sk8 * 8;
            const unsigned short* gb = B + (n0 + row) * HIDDEN + kb * 64 + sk8 * 8;
            __builtin_amdgcn_global_load_lds(
                (const __attribute__((address_space(1))) void*)ga,
                (__attribute__((address_space(3))) void*)(&lA[buf][c * 8]), 16, 0, 0);
            __builtin_amdgcn_global_load_lds(
                (const __attribute__((address_space(1))) void*)gb,
                (__attribute__((address_space(3))) void*)(&lB[buf][c * 8]), 16, 0, 0);
        }
    };

    stage(0, 0);
    __syncthreads();                         // drains stage(0)

#pragma unroll
    for (int kb = 0; kb < 4; ++kb) {
        if (kb < 3) stage(kb + 1, (kb + 1) & 1);   // overlap loads with compute
        const unsigned short* bufA = lA[kb & 1];
        const unsigned short* bufB = lB[kb & 1];
#pragma unroll
        for (int ki = 0; ki < 2; ++ki) {
            short8 af[4], bf[4];
#pragma unroll
            for (int i = 0; i < 4; ++i) {
                const int ra = wm + 16 * i + l15;
                af[i] = *(const short8*)
                    &bufA[ra * 64 + (((ki * 4 + quad) ^ (ra & 7)) * 8)];
                const int rb = wn + 16 * i + l15;
                bf[i] = *(const short8*)
                    &bufB[rb * 64 + (((ki * 4 + quad) ^ (rb & 7)) * 8)];
            }
#pragma unroll
            for (int i = 0; i < 4; ++i)
#pragma unroll
                for (int j = 0; j < 4; ++j)
                    acc[i][j] = __builtin_amdgcn_mfma_f32_16x16x32_bf16(
                        af[i], bf[j], acc[i][j], 0, 0, 0);
        }
        if (kb < 3) __syncthreads();
    }

    // epilogue: C/D layout col = lane&15, row = quad*4 + reg.  Nontemporal:
    // C is never re-read; bypass L2.
#pragma unroll
    for (int j = 0; j < 4; ++j) {
        const long col = n0 + wn + 16 * j + l15;
        if (col < VOCAB) {
            const float bv = bias[col];
#pragma unroll
            for (int i = 0; i < 4; ++i) {
                const long row = m0 + wm + 16 * i + quad * 4;
                float* Cp = C + row * VOCAB + col;
#pragma unroll
                for (int r = 0; r < 4; ++r)
                    __builtin_nontemporal_store(acc[i][j][r] + bv,
                                                Cp + (long)r * VOCAB);
            }
        }
    }
}

// ---------------------------------------------------------------------------
extern "C" void kernel_launch(void* const* d_in, const int* in_sizes, int n_in,
                              void* d_out, int out_size, void* d_ws, size_t ws_size,
                              hipStream_t stream) {
    const int*   inputs = (const int*)  d_in[0];
    const float* state  = (const float*)d_in[1];
    const float* W_ih   = (const float*)d_in[2];
    const float* b_ih   = (const float*)d_in[3];
    const float* W_hh   = (const float*)d_in[4];
    const float* b_hh   = (const float*)d_in[5];
    const float* W_out  = (const float*)d_in[6];
    const float* b_out  = (const float*)d_in[7];
    float* out = (float*)d_out;

    char* ws = (char*)d_ws;
    float*          W_ihT = (float*)ws;                        // 10,240,000 B
    unsigned short* Wb    = (unsigned short*)(ws + 10240000);  //  5,177,344 B
    unsigned short* Ybf   = (unsigned short*)(ws + 15417344);  //  4,194,304 B

    prep_kernel<<<PREP_BLOCKS, 256, 0, stream>>>(W_ih, W_ihT, W_out, Wb);
    scan_kernel<<<BATCH, 512, 0, stream>>>(inputs, state, W_hh, b_ih, b_hh,
                                           W_ihT, Ybf, out + LOGITS_ELEMS);
    gemm_kernel<<<MTILES * NTILES, 256, 0, stream>>>(Ybf, Wb, b_out, out);
}